// Round 7
// baseline (908.878 us; speedup 1.0000x reference)
//
#include <hip/hip_runtime.h>
#include <math.h>

#define NE 64
#define NTOK 16384
#define DD 4096
#define TOPK 2
#define BLOCK 512            // 8 waves = 2 expert-halves x 4 K-quarters
#define TOKPB 64
#define KQn 4
#define KRANGE (DD / KQn)    // 1024 k per quarter
#define KC 16                // k per chunk (one 64B line per row)
#define NCH (KRANGE / KC)    // 64 chunks
#define WROWS 32             // expert rows per wave (its eg-half)
#define WBUF (WROWS * KC)    // 512 dwords = 2KB per wave
#define LGSTR 68             // logit plane row stride
#define LGKQ (64 * LGSTR)    // 4352 dwords per kq plane
#define SMEM_DW (KQn * LGKQ) // 17408 dwords = 69.6 KB (weights alias first 16KB)

// grid = 256 = 1 block/CU (2 waves/SIMD). amdgpu_waves_per_eu(1,2) CAPS the
// allocator's occupancy target at 2 waves/EU -> 256-VGPR budget (launch_bounds'
// 2nd arg only sets a MINIMUM; R4-R6 showed the heuristic parks at 128 and
// spills). Live set ~205 regs.
__attribute__((amdgpu_flat_work_group_size(BLOCK, BLOCK),
               amdgpu_waves_per_eu(1, 2)))
__global__ void router_kernel(
    const float* __restrict__ x, const float* __restrict__ gw,
    float* __restrict__ out, float* __restrict__ ws) {
  __shared__ __align__(16) float smem[SMEM_DW];

  const int tid = threadIdx.x;
  const int lane = tid & 63;
  const int wid = __builtin_amdgcn_readfirstlane(tid >> 6);
  const int eg = wid & 1;   // expert half: experts eg*32 .. eg*32+31
  const int kq = wid >> 1;  // K quarter
  const int g = lane >> 3;  // expert sub-row 0..7 (experts eg*32 + g + 8j)
  const int s = lane & 7;   // token slot (tokens s + 8t, t=0..7)
  const int g3 = g & 3;
  const int tok0 = blockIdx.x * TOKPB;

  // per-token x row pointers (8 tokens per lane; dup across g -> coalescer dedup)
  const float* xt[8];
#pragma unroll
  for (int t = 0; t < 8; ++t)
    xt[t] = x + (size_t)(tok0 + s + 8 * t) * DD + kq * KRANGE;

  // weight staging: lane l stages 16B pieces; LDS dest LINEAR (dst = wbase+l*4),
  // source pre-swizzled so read slot (q^g3) of row r holds global quad q.
  const int r0 = lane >> 2;  // 0..15
  const int q1 = lane & 3;
  const int sw = q1 ^ (r0 & 3);
  const float* ws0 = gw + (size_t)(eg * 32 + r0) * DD + kq * KRANGE + sw * 4;
  const float* ws1 = ws0 + (size_t)16 * DD;  // row r0+16 (same swizzle)
  const int wbase = wid * WBUF;
  const int dst0 = wbase + lane * 4;        // linear
  const int dst1 = dst0 + 256;              // +16 rows

  // per-quad swizzled read bases (dwords): row g, slot q^g3; +j*128 for row g+8j
  int wq[4];
#pragma unroll
  for (int q = 0; q < 4; ++q) wq[q] = wbase + g * 16 + ((q ^ g3) << 2);

  float acc[8][4];
#pragma unroll
  for (int t = 0; t < 8; ++t)
#pragma unroll
    for (int j = 0; j < 4; ++j) acc[t][j] = 0.f;

  // prologue: weight chunk 0 in regs; x pair 0 (quads 0,1) in regs
  float4 st0 = *(const float4*)ws0;
  float4 st1 = *(const float4*)ws1;
  float4 pa[8], pb[8], na[8], nb[8];
#pragma unroll
  for (int t = 0; t < 8; ++t) {
    pa[t] = *(const float4*)(xt[t] + 0);
    pb[t] = *(const float4*)(xt[t] + 4);
  }

#define QUAD(QL, XV)                                                     \
  do {                                                                   \
    const float4 w0 = *(const float4*)&smem[wq[QL] + 0 * 128];           \
    const float4 w1 = *(const float4*)&smem[wq[QL] + 1 * 128];           \
    const float4 w2 = *(const float4*)&smem[wq[QL] + 2 * 128];           \
    const float4 w3 = *(const float4*)&smem[wq[QL] + 3 * 128];           \
    _Pragma("unroll") for (int t = 0; t < 8; ++t) {                      \
      const float4 xv = XV[t];                                           \
      acc[t][0] = fmaf(xv.x, w0.x, acc[t][0]);                           \
      acc[t][0] = fmaf(xv.y, w0.y, acc[t][0]);                           \
      acc[t][0] = fmaf(xv.z, w0.z, acc[t][0]);                           \
      acc[t][0] = fmaf(xv.w, w0.w, acc[t][0]);                           \
      acc[t][1] = fmaf(xv.x, w1.x, acc[t][1]);                           \
      acc[t][1] = fmaf(xv.y, w1.y, acc[t][1]);                           \
      acc[t][1] = fmaf(xv.z, w1.z, acc[t][1]);                           \
      acc[t][1] = fmaf(xv.w, w1.w, acc[t][1]);                           \
      acc[t][2] = fmaf(xv.x, w2.x, acc[t][2]);                           \
      acc[t][2] = fmaf(xv.y, w2.y, acc[t][2]);                           \
      acc[t][2] = fmaf(xv.z, w2.z, acc[t][2]);                           \
      acc[t][2] = fmaf(xv.w, w2.w, acc[t][2]);                           \
      acc[t][3] = fmaf(xv.x, w3.x, acc[t][3]);                           \
      acc[t][3] = fmaf(xv.y, w3.y, acc[t][3]);                           \
      acc[t][3] = fmaf(xv.z, w3.z, acc[t][3]);                           \
      acc[t][3] = fmaf(xv.w, w3.w, acc[t][3]);                           \
    }                                                                    \
  } while (0)

#pragma unroll 1
  for (int c = 0; c < NCH; ++c) {
    const int base = c * KC;
    // write chunk c weights to this wave's private buffer (in-order DS:
    // prior chunk's reads retire first; no barrier needed)
    *(float4*)&smem[dst0] = st0;
    *(float4*)&smem[dst1] = st1;
    if (c + 1 < NCH) {  // global loads for chunk c+1 (latency hidden by chunk)
      st0 = *(const float4*)(ws0 + (c + 1) * KC);
      st1 = *(const float4*)(ws1 + (c + 1) * KC);
    }
    // issue x pair1 (quads 2,3) loads, compute pair0 (quads 0,1)
#pragma unroll
    for (int t = 0; t < 8; ++t) {
      na[t] = *(const float4*)(xt[t] + base + 8);
      nb[t] = *(const float4*)(xt[t] + base + 12);
    }
    QUAD(0, pa);
    QUAD(1, pb);
    // issue x pair0 of next chunk, compute pair1
    if (c + 1 < NCH) {
#pragma unroll
      for (int t = 0; t < 8; ++t) {
        pa[t] = *(const float4*)(xt[t] + base + 16);
        pb[t] = *(const float4*)(xt[t] + base + 20);
      }
    }
    QUAD(2, na);
    QUAD(3, nb);
    // pacing barrier ONLY (no memory semantics; w-staging is wave-private):
    // keeps the eg-twin waves lockstepped so their identical x lines hit L1
    // instead of doubling HBM fetch (R6: FETCH was 2.9x ideal from drift).
    __builtin_amdgcn_s_barrier();
  }
#undef QUAD

  __syncthreads();  // all compute done; weight buffers die, planes alias

  // partial logits: plane[kq][tok 64][LGSTR]; expert col = eg*32 + g + 8j
#pragma unroll
  for (int t = 0; t < 8; ++t) {
    float* row = &smem[kq * LGKQ + (s + 8 * t) * LGSTR + eg * 32 + g];
#pragma unroll
    for (int j = 0; j < 4; ++j) row[8 * j] = acc[t][j];
  }
  __syncthreads();

  // epilogue: wave wid -> tokens wid*8..+7; lane == expert
  float psum_local = 0.f, cnt_local = 0.f;
  float* out_v = out;                // (NTOK, 2) top-k vals
  float* out_i = out + NTOK * TOPK;  // (NTOK, 2) top-k idx as float
#pragma unroll 1
  for (int ii = 0; ii < 8; ++ii) {
    const int t = wid * 8 + ii;
    float v = smem[0 * LGKQ + t * LGSTR + lane] +
              smem[1 * LGKQ + t * LGSTR + lane] +
              smem[2 * LGKQ + t * LGSTR + lane] +
              smem[3 * LGKQ + t * LGSTR + lane];
    float m = v;
#pragma unroll
    for (int sh = 32; sh > 0; sh >>= 1) m = fmaxf(m, __shfl_xor(m, sh, 64));
    float ex = expf(v - m);
    float ssum = ex;
#pragma unroll
    for (int sh = 32; sh > 0; sh >>= 1) ssum += __shfl_xor(ssum, sh, 64);
    float p = ex / ssum;
    psum_local += p;

    float v1 = p; int i1 = lane;  // top-1, ties -> lowest index
#pragma unroll
    for (int sh = 32; sh > 0; sh >>= 1) {
      float ov = __shfl_xor(v1, sh, 64);
      int oi = __shfl_xor(i1, sh, 64);
      if (ov > v1 || (ov == v1 && oi < i1)) { v1 = ov; i1 = oi; }
    }
    float v2 = (lane == i1) ? -INFINITY : p; int i2 = lane;  // top-2
#pragma unroll
    for (int sh = 32; sh > 0; sh >>= 1) {
      float ov = __shfl_xor(v2, sh, 64);
      int oi = __shfl_xor(i2, sh, 64);
      if (ov > v2 || (ov == v2 && oi < i2)) { v2 = ov; i2 = oi; }
    }
    cnt_local += (lane == i1 ? 1.f : 0.f) + (lane == i2 ? 1.f : 0.f);
    if (lane == 0) {
      const int tg = tok0 + t;
      out_v[tg * 2 + 0] = v1;
      out_v[tg * 2 + 1] = v2;
      out_i[tg * 2 + 0] = (float)i1;
      out_i[tg * 2 + 1] = (float)i2;
    }
  }
  // loss partials: ws[0:64] = pick counts, ws[64:128] = prob sums
  atomicAdd(ws + lane, cnt_local);
  atomicAdd(ws + NE + lane, psum_local);
}

__global__ void loss_kernel(const float* __restrict__ ws,
                            float* __restrict__ out) {
  const int lane = threadIdx.x & 63;
  float f = ws[lane] * (1.f / (float)(NTOK * TOPK));
  float p = ws[NE + lane] * (1.f / (float)NTOK);
  float v = f * p;  // loss = E * mean_i(f_i p_i) = sum_i f_i p_i
#pragma unroll
  for (int sh = 32; sh > 0; sh >>= 1) v += __shfl_xor(v, sh, 64);
  if (lane == 0) out[NTOK * TOPK * 2] = v;
}

extern "C" void kernel_launch(void* const* d_in, const int* in_sizes, int n_in,
                              void* d_out, int out_size, void* d_ws,
                              size_t ws_size, hipStream_t stream) {
  const float* x = (const float*)d_in[0];
  const float* gw = (const float*)d_in[1];
  float* out = (float*)d_out;
  float* ws = (float*)d_ws;

  hipMemsetAsync(d_ws, 0, 2 * NE * sizeof(float), stream);
  router_kernel<<<NTOK / TOKPB, BLOCK, 0, stream>>>(x, gw, out, ws);
  loss_kernel<<<1, 64, 0, stream>>>(ws, out);
}

// Round 8
// 208.424 us; speedup vs baseline: 4.3607x; 4.3607x over previous
//
#include <hip/hip_runtime.h>
#include <math.h>

#define NE 64
#define NTOK 16384
#define DD 4096
#define TOPK 2
#define BLOCK 512            // 8 waves = 2 expert-halves x 4 K-quarters
#define TOKPB 64
#define KQn 4
#define KRANGE (DD / KQn)    // 1024 k per quarter
#define KC 16                // k per chunk
#define NCH (KRANGE / KC)    // 64 chunks
#define LGSTR 68             // logit plane row stride (dwords)
#define LGKQ (64 * LGSTR)    // 4352 dwords per kq plane
#define SMEM_DW (KQn * LGKQ) // 17408 dw = 69.6 KB; staging aliases [0,16384)

// LDS staging map (dwords):
//   x: BUF*4096 + kq*1024 + tok*16 + slot*4      -> [0, 8192)
//   w: 8192 + BUF*4096 + kq*1024 + exp*16 + slot*4 -> [8192, 16384)
// Content swizzle (source-side; DMA dest is linear, rule #21):
//   slot j of row r holds global quad j ^ (r&3).

__device__ __forceinline__ void dma16(const float* g, float* l) {
  __builtin_amdgcn_global_load_lds(
      (const __attribute__((address_space(1))) void*)g,
      (__attribute__((address_space(3))) void*)l, 16, 0, 0);
}

__global__ __launch_bounds__(BLOCK) void router_kernel(
    const float* __restrict__ x, const float* __restrict__ gw,
    float* __restrict__ out, float* __restrict__ ws) {
  __shared__ __align__(16) float smem[SMEM_DW];

  const int tid = threadIdx.x;
  const int lane = tid & 63;
  const int wid = __builtin_amdgcn_readfirstlane(tid >> 6);
  const int eg = wid & 1;   // expert half / staging half
  const int kq = wid >> 1;  // K quarter
  const int g = lane >> 3;  // expert sub-row (experts eg*32 + g + 8*jj)
  const int s = lane & 7;   // token slot (tokens s + 8*t)
  const int tok0 = blockIdx.x * TOKPB;

  // ---- staging addressing (per-lane global, wave-uniform LDS dest) ----
  const int sr = lane >> 2;                  // sub-row 0..15 within inst
  const int sq = (lane & 3) ^ (sr & 3);      // pre-swizzled source quad
  const float* pgx0 = x + (size_t)(tok0 + 32 * eg + sr) * DD + kq * KRANGE + sq * 4;
  const float* pgx1 = pgx0 + (size_t)16 * DD;
  const float* pgw0 = gw + (size_t)(32 * eg + sr) * DD + kq * KRANGE + sq * 4;
  const float* pgw1 = pgw0 + (size_t)16 * DD;
  const int ddx0 = kq * 1024 + eg * 512;          // + BUF*4096
  const int ddx1 = ddx0 + 256;
  const int ddw0 = 8192 + kq * 1024 + eg * 512;   // + BUF*4096
  const int ddw1 = ddw0 + 256;

  // ---- compute read bases (offsets beyond these are compile-time imms) ----
  const int sA = s & 3, gA = g & 3;
  const int bxc = kq * 1024 + s * 16;
  const int bwc = 8192 + kq * 1024 + (eg * 32 + g) * 16;
  const int bx0 = bxc + ((0 ^ sA) << 2), bx1 = bxc + ((1 ^ sA) << 2);
  const int bx2 = bxc + ((2 ^ sA) << 2), bx3 = bxc + ((3 ^ sA) << 2);
  const int bw0 = bwc + ((0 ^ gA) << 2), bw1 = bwc + ((1 ^ gA) << 2);
  const int bw2 = bwc + ((2 ^ gA) << 2), bw3 = bwc + ((3 ^ gA) << 2);

  float acc[8][4];
#pragma unroll
  for (int t = 0; t < 8; ++t)
#pragma unroll
    for (int j = 0; j < 4; ++j) acc[t][j] = 0.f;

#define ISSUE(CC, BUF)                                              \
  do {                                                              \
    dma16(pgx0 + (CC) * 16, &smem[(BUF) * 4096 + ddx0]);            \
    dma16(pgx1 + (CC) * 16, &smem[(BUF) * 4096 + ddx1]);            \
    dma16(pgw0 + (CC) * 16, &smem[(BUF) * 4096 + ddw0]);            \
    dma16(pgw1 + (CC) * 16, &smem[(BUF) * 4096 + ddw1]);            \
  } while (0)

#define QUADC(BUF, Q)                                               \
  do {                                                              \
    const float4 w0 = *(const float4*)&smem[bw##Q + (BUF) * 4096 + 0];   \
    const float4 w1 = *(const float4*)&smem[bw##Q + (BUF) * 4096 + 128]; \
    const float4 w2 = *(const float4*)&smem[bw##Q + (BUF) * 4096 + 256]; \
    const float4 w3 = *(const float4*)&smem[bw##Q + (BUF) * 4096 + 384]; \
    _Pragma("unroll") for (int t = 0; t < 8; ++t) {                 \
      const float4 xv = *(const float4*)&smem[bx##Q + (BUF) * 4096 + t * 128]; \
      acc[t][0] = fmaf(xv.x, w0.x, acc[t][0]);                      \
      acc[t][0] = fmaf(xv.y, w0.y, acc[t][0]);                      \
      acc[t][0] = fmaf(xv.z, w0.z, acc[t][0]);                      \
      acc[t][0] = fmaf(xv.w, w0.w, acc[t][0]);                      \
      acc[t][1] = fmaf(xv.x, w1.x, acc[t][1]);                      \
      acc[t][1] = fmaf(xv.y, w1.y, acc[t][1]);                      \
      acc[t][1] = fmaf(xv.z, w1.z, acc[t][1]);                      \
      acc[t][1] = fmaf(xv.w, w1.w, acc[t][1]);                      \
      acc[t][2] = fmaf(xv.x, w2.x, acc[t][2]);                      \
      acc[t][2] = fmaf(xv.y, w2.y, acc[t][2]);                      \
      acc[t][2] = fmaf(xv.z, w2.z, acc[t][2]);                      \
      acc[t][2] = fmaf(xv.w, w2.w, acc[t][2]);                      \
      acc[t][3] = fmaf(xv.x, w3.x, acc[t][3]);                      \
      acc[t][3] = fmaf(xv.y, w3.y, acc[t][3]);                      \
      acc[t][3] = fmaf(xv.z, w3.z, acc[t][3]);                      \
      acc[t][3] = fmaf(xv.w, w3.w, acc[t][3]);                      \
    }                                                               \
  } while (0)

  // per chunk: issue next-chunk DMA, counted vmcnt (loads stay in flight
  // across barriers -- never vmcnt(0) mid-loop), raw barriers (no drain).
#define CHUNK(CC, BUF)                                              \
  do {                                                              \
    if ((CC) + 1 < NCH) {                                           \
      ISSUE((CC) + 1, (BUF) ^ 1);                                   \
      asm volatile("s_waitcnt vmcnt(4)" ::: "memory");              \
    } else {                                                        \
      asm volatile("s_waitcnt vmcnt(0)" ::: "memory");              \
    }                                                               \
    __builtin_amdgcn_s_barrier();                                   \
    QUADC(BUF, 0);                                                  \
    QUADC(BUF, 1);                                                  \
    QUADC(BUF, 2);                                                  \
    QUADC(BUF, 3);                                                  \
    __builtin_amdgcn_s_barrier();                                   \
  } while (0)

  ISSUE(0, 0);  // prologue: chunk 0 -> buf 0
#pragma unroll 1
  for (int c = 0; c < NCH; c += 2) {
    CHUNK(c, 0);
    CHUNK(c + 1, 1);
  }
#undef CHUNK
#undef QUADC
#undef ISSUE

  __syncthreads();  // staging buffers die; planes alias them

  // partial logits: plane[kq][tok][LGSTR], expert col = eg*32 + g + 8*jj
#pragma unroll
  for (int t = 0; t < 8; ++t) {
    float* row = &smem[kq * LGKQ + (s + 8 * t) * LGSTR + eg * 32 + g];
    row[0] = acc[t][0];
    row[8] = acc[t][1];
    row[16] = acc[t][2];
    row[24] = acc[t][3];
  }
  __syncthreads();

  // epilogue: wave wid -> tokens wid*8..+7; lane == expert
  float psum_local = 0.f, cnt_local = 0.f;
  float* out_v = out;                // (NTOK, 2) top-k vals
  float* out_i = out + NTOK * TOPK;  // (NTOK, 2) top-k idx as float
#pragma unroll 1
  for (int ii = 0; ii < 8; ++ii) {
    const int t = wid * 8 + ii;
    float v = smem[0 * LGKQ + t * LGSTR + lane] +
              smem[1 * LGKQ + t * LGSTR + lane] +
              smem[2 * LGKQ + t * LGSTR + lane] +
              smem[3 * LGKQ + t * LGSTR + lane];
    float m = v;
#pragma unroll
    for (int sh = 32; sh > 0; sh >>= 1) m = fmaxf(m, __shfl_xor(m, sh, 64));
    float ex = expf(v - m);
    float ssum = ex;
#pragma unroll
    for (int sh = 32; sh > 0; sh >>= 1) ssum += __shfl_xor(ssum, sh, 64);
    float p = ex / ssum;
    psum_local += p;

    float v1 = p; int i1 = lane;  // top-1, ties -> lowest index
#pragma unroll
    for (int sh = 32; sh > 0; sh >>= 1) {
      float ov = __shfl_xor(v1, sh, 64);
      int oi = __shfl_xor(i1, sh, 64);
      if (ov > v1 || (ov == v1 && oi < i1)) { v1 = ov; i1 = oi; }
    }
    float v2 = (lane == i1) ? -INFINITY : p; int i2 = lane;  // top-2
#pragma unroll
    for (int sh = 32; sh > 0; sh >>= 1) {
      float ov = __shfl_xor(v2, sh, 64);
      int oi = __shfl_xor(i2, sh, 64);
      if (ov > v2 || (ov == v2 && oi < i2)) { v2 = ov; i2 = oi; }
    }
    cnt_local += (lane == i1 ? 1.f : 0.f) + (lane == i2 ? 1.f : 0.f);
    if (lane == 0) {
      const int tg = tok0 + t;
      out_v[tg * 2 + 0] = v1;
      out_v[tg * 2 + 1] = v2;
      out_i[tg * 2 + 0] = (float)i1;
      out_i[tg * 2 + 1] = (float)i2;
    }
  }
  // loss partials: ws[0:64] = pick counts, ws[64:128] = prob sums
  atomicAdd(ws + lane, cnt_local);
  atomicAdd(ws + NE + lane, psum_local);
}

__global__ void loss_kernel(const float* __restrict__ ws,
                            float* __restrict__ out) {
  const int lane = threadIdx.x & 63;
  float f = ws[lane] * (1.f / (float)(NTOK * TOPK));
  float p = ws[NE + lane] * (1.f / (float)NTOK);
  float v = f * p;  // loss = E * mean_i(f_i p_i) = sum_i f_i p_i
#pragma unroll
  for (int sh = 32; sh > 0; sh >>= 1) v += __shfl_xor(v, sh, 64);
  if (lane == 0) out[NTOK * TOPK * 2] = v;
}

extern "C" void kernel_launch(void* const* d_in, const int* in_sizes, int n_in,
                              void* d_out, int out_size, void* d_ws,
                              size_t ws_size, hipStream_t stream) {
  const float* x = (const float*)d_in[0];
  const float* gw = (const float*)d_in[1];
  float* out = (float*)d_out;
  float* ws = (float*)d_ws;

  hipMemsetAsync(d_ws, 0, 2 * NE * sizeof(float), stream);
  router_kernel<<<NTOK / TOKPB, BLOCK, 0, stream>>>(x, gw, out, ws);
  loss_kernel<<<1, 64, 0, stream>>>(ws, out);
}